// Round 16
// baseline (440.188 us; speedup 1.0000x reference)
//
#include <hip/hip_runtime.h>

#define DIM   128
#define DMASK 127
#define PLANE (DIM * DIM)     // 16384
#define VOX   (1 << 21)       // 128^3
#define NCH   12

// De-aliased layout (validated r12: 199->142 us): channel stride 4MB+4KB,
// image stride +2KB more. Keeps the 24 stream bases off one channel slot.
#define CHS   (VOX + 2048)
#define IMGS  (NCH * CHS + 1024)

typedef __attribute__((ext_vector_type(2))) _Float16 half2v;
typedef __attribute__((ext_vector_type(8))) _Float16 half8v;

// Per-channel shift pairs (d,h,w) = 2*(one_hot_idx - 1); verified (absmax 0).
__constant__ int c_sd1[12] = { 0, 0, 0, 0, 0, 2, 2, 2, 0, 0, 0, 0};
__constant__ int c_sh1[12] = { 0,-2,-2, 0, 0, 0, 0, 0, 2, 2, 2, 2};
__constant__ int c_sw1[12] = {-2, 0, 0, 2, 2, 0, 0, 0, 0, 0, 0, 0};
__constant__ int c_sd2[12] = {-2,-2, 0,-2, 0, 0, 0, 0,-2, 0, 0, 2};
__constant__ int c_sh2[12] = { 0, 0, 0, 0,-2, 0,-2, 0, 0, 0, 0, 0};
__constant__ int c_sw2[12] = { 0, 0,-2, 0, 0,-2, 0, 2, 0,-2, 2, 0};

__device__ __forceinline__ int clamp7(int v) { return min(max(v, 0), DMASK); }

// F123 v6: wave-autonomous (zero LDS/barriers, validated r15), now with
// dseg=8 (12 planes per wave) and 6 waves/EU so 24 waves/CU are resident —
// r15 was grid-limited to 12 waves/CU (occupancy 24.7%, VALUBusy 48%).
__global__ __launch_bounds__(256, 6) void f123(const float* __restrict__ img0,
                                               const float* __restrict__ img1,
                                               _Float16* __restrict__ Sall) {
    const float* img = blockIdx.y ? img1 : img0;
    _Float16* outS = Sall + (size_t)blockIdx.y * IMGS;
    const char* imgc = (const char*)img;

    int wid = (blockIdx.x << 2) + (threadIdx.x >> 6);  // 0..3071
    int ch = wid >> 8;                 // 12
    int hs = (wid >> 4) & 15;          // 16 h-slices of 8 rows
    int ds = wid & 15;                 // 16 d-segs of 8 planes
    int h0 = hs << 3;
    int d0 = ds << 3;
    int l  = threadIdx.x & 63;

    int sd1 = c_sd1[ch], sh1 = c_sh1[ch], sw1 = c_sw1[ch];
    int sd2 = c_sd2[ch], sh2 = c_sh2[ch], sw2 = c_sw2[ch];

    // wave-uniform row byte-offsets (double clamp composed), 12 rows
    int rowOffA[12], rowOffB[12];
#pragma unroll
    for (int r = 0; r < 12; ++r) {
        int hq = clamp7(h0 - 2 + r);
        rowOffA[r] = clamp7(hq + sh1) * (DIM * 4);
        rowOffB[r] = clamp7(hq + sh2) * (DIM * 4);
    }

    // per-lane column byte bases (float2 at cols 2l+sw, clamped to [0,126])
    int c2 = l << 1;
    int colA = min(max(c2 + sw1, 0), 126) * 4;
    int colB = min(max(c2 + sw2, 0), 126) * 4;
    bool fixAlo = (sw1 < 0) && (l == 0);   // need (v0,v0): a.y = a.x
    bool fixAhi = (sw1 > 0) && (l == 63);  // need (v127,v127): a.x = a.y
    bool fixBlo = (sw2 < 0) && (l == 0);
    bool fixBhi = (sw2 > 0) && (l == 63);

    float2 win[8];
    half2v hist[5][8];
#pragma unroll
    for (int k = 0; k < 8; ++k) {
        win[k].x = 0.0f; win[k].y = 0.0f;
#pragma unroll
        for (int s = 0; s < 5; ++s) hist[s][k] = half2v{(_Float16)0.0f, (_Float16)0.0f};
    }

    _Float16* dstBase = outS + (size_t)ch * CHS + h0 * DIM + c2;

#pragma unroll
    for (int it = 0; it < 12; ++it) {          // 8 outputs + 4 halo planes
        const int s5 = it % 5;                 // static hist slot (full unroll)
        int dp = clamp7(d0 - 2 + it);
        int pOffA = clamp7(dp + sd1) * (PLANE * 4);
        int pOffB = clamp7(dp + sd2) * (PLANE * 4);

        float tX[12], tY[12];
#pragma unroll
        for (int r = 0; r < 12; ++r) {
            float2 a = *(const float2*)(imgc + (pOffA + rowOffA[r] + colA));
            float2 b = *(const float2*)(imgc + (pOffB + rowOffB[r] + colB));
            a.y = fixAlo ? a.x : a.y;  a.x = fixAhi ? a.y : a.x;
            b.y = fixBlo ? b.x : b.y;  b.x = fixBhi ? b.y : b.x;
            float dx = a.x - b.x; dx *= dx;      // D2[2l]
            float dy = a.y - b.y; dy *= dy;      // D2[2l+1]
            float lx = __shfl_up(dx, 1, 64);     // D2[2l-2]
            float ly = __shfl_up(dy, 1, 64);     // D2[2l-1]
            float rx = __shfl_down(dx, 1, 64);   // D2[2l+2]
            float ry = __shfl_down(dy, 1, 64);   // D2[2l+3]
            ly = (l == 0)  ? dx : ly;            // D2[-1 -> 0]
            rx = (l == 63) ? dy : rx;            // D2[128 -> 127]
            tX[r] = lx + ly + dx + dy + rx;      // W-box(2l)
            tY[r] = ly + dx + dy + rx + ry;      // W-box(2l+1)
        }

        // H-box sliding 5-row sums + D-window update
        float sx = tX[0] + tX[1] + tX[2] + tX[3] + tX[4];
        float sy = tY[0] + tY[1] + tY[2] + tY[3] + tY[4];
        bool dowrite = (it >= 4);
        _Float16* dstD = dstBase + (size_t)(d0 + it - 4) * PLANE;
#pragma unroll
        for (int k = 0; k < 8; ++k) {
            half2v hv = { (_Float16)sx, (_Float16)sy };  // round first (validated)
            half2v old = hist[s5][k];
            win[k].x += (float)hv[0] - (float)old[0];
            win[k].y += (float)hv[1] - (float)old[1];
            hist[s5][k] = hv;
            if (dowrite) {
                half2v ov = { (_Float16)win[k].x, (_Float16)win[k].y };
                *(half2v*)(dstD + k * DIM) = ov;
            }
            if (k < 7) {
                sx += tX[k + 5] - tX[k];
                sy += tY[k + 5] - tY[k];
            }
        }
    }
}

// kmse v7: 8 vox/thread, 24 independent 16-B half8v loads (1 KB/wave-inst),
// e0 overwrites the v0 registers (fp16 e0 validated r5-r9), no atomics.
__global__ __launch_bounds__(256, 3) void kmse(const _Float16* __restrict__ S0,
                                               const _Float16* __restrict__ S1,
                                               float* __restrict__ partial) {
    int t = blockIdx.x * 256 + threadIdx.x;       // 1024 blocks

    float mn[8], sm[8];
    half8v v[NCH];

    // ---- img0: 12 fat loads, min/sum, e0 in place ----
#pragma unroll
    for (int ch = 0; ch < NCH; ++ch)
        v[ch] = ((const half8v*)(S0 + (size_t)ch * CHS))[t];
#pragma unroll
    for (int j = 0; j < 8; ++j) { mn[j] = 3.4e38f; sm[j] = 0.0f; }
#pragma unroll
    for (int ch = 0; ch < NCH; ++ch)
#pragma unroll
        for (int j = 0; j < 8; ++j) {
            float s = (float)v[ch][j];
            mn[j] = fminf(mn[j], s); sm[j] += s;
        }
    float inv[8];
#pragma unroll
    for (int j = 0; j < 8; ++j)
        inv[j] = __fdividef(1.0f, sm[j] * (1.0f / 12.0f) - mn[j]);
    half8v e0[NCH];
#pragma unroll
    for (int ch = 0; ch < NCH; ++ch) {
        half8v e;
#pragma unroll
        for (int j = 0; j < 8; ++j)
            e[j] = (_Float16)__expf(-((float)v[ch][j] - mn[j]) * inv[j]);
        e0[ch] = e;
    }

    // ---- img1: 12 fat loads, min/sum ----
#pragma unroll
    for (int ch = 0; ch < NCH; ++ch)
        v[ch] = ((const half8v*)(S1 + (size_t)ch * CHS))[t];
#pragma unroll
    for (int j = 0; j < 8; ++j) { mn[j] = 3.4e38f; sm[j] = 0.0f; }
#pragma unroll
    for (int ch = 0; ch < NCH; ++ch)
#pragma unroll
        for (int j = 0; j < 8; ++j) {
            float s = (float)v[ch][j];
            mn[j] = fminf(mn[j], s); sm[j] += s;
        }
#pragma unroll
    for (int j = 0; j < 8; ++j)
        inv[j] = __fdividef(1.0f, sm[j] * (1.0f / 12.0f) - mn[j]);

    // ---- MSE ----
    float acc = 0.0f;
#pragma unroll
    for (int ch = 0; ch < NCH; ++ch)
#pragma unroll
        for (int j = 0; j < 8; ++j) {
            float e1 = __expf(-((float)v[ch][j] - mn[j]) * inv[j]);
            float df = (float)e0[ch][j] - e1;
            acc += df * df;
        }

#pragma unroll
    for (int off = 32; off > 0; off >>= 1)
        acc += __shfl_down(acc, off, 64);
    __shared__ float smem[4];
    int lane = threadIdx.x & 63, wv = threadIdx.x >> 6;
    if (lane == 0) smem[wv] = acc;
    __syncthreads();
    if (threadIdx.x == 0)
        partial[blockIdx.x] = smem[0] + smem[1] + smem[2] + smem[3];
}

// kred: sum 1024 partials, write the final scalar.
__global__ __launch_bounds__(256) void kred(const float* __restrict__ partial,
                                            float* __restrict__ out) {
    int tid = threadIdx.x;
    float acc = partial[tid] + partial[tid + 256]
              + partial[tid + 512] + partial[tid + 768];
#pragma unroll
    for (int off = 32; off > 0; off >>= 1)
        acc += __shfl_down(acc, off, 64);
    __shared__ float smem[4];
    int lane = tid & 63, wv = tid >> 6;
    if (lane == 0) smem[wv] = acc;
    __syncthreads();
    if (tid == 0)
        out[0] = (smem[0] + smem[1] + smem[2] + smem[3])
               * (1.0f / (12.0f * (float)VOX));
}

__global__ void kdiag(float* out, float ws_mb) { out[0] = ws_mb; }

extern "C" void kernel_launch(void* const* d_in, const int* in_sizes, int n_in,
                              void* d_out, int out_size, void* d_ws, size_t ws_size,
                              hipStream_t stream) {
    const float* y_true = (const float*)d_in[0];
    const float* y_pred = (const float*)d_in[1];
    float* out = (float*)d_out;

    const size_t NEED = 2ull * IMGS * sizeof(_Float16) + 8192 + 64;  // ~96.2 MB
    if (ws_size < NEED) {
        kdiag<<<1, 1, 0, stream>>>(out, (float)(ws_size >> 20));
        return;
    }

    _Float16* S0      = (_Float16*)d_ws;            // ssd img0 (padded layout)
    _Float16* S1      = S0 + (size_t)IMGS;          // ssd img1
    float*    partial = (float*)(S1 + (size_t)IMGS);// 1024 floats

    // 3072 wave-tasks per image (12 ch x 16 hslices x 16 dsegs), 4 waves/block
    f123<<<dim3(768, 2), 256, 0, stream>>>(y_true, y_pred, S0);
    kmse<<<VOX / 8 / 256, 256, 0, stream>>>(S0, S1, partial);
    kred<<<1, 256, 0, stream>>>(partial, out);
}

// Round 17
// 137.856 us; speedup vs baseline: 3.1931x; 3.1931x over previous
//
#include <hip/hip_runtime.h>

#define DIM   128
#define DMASK 127
#define PLANE (DIM * DIM)     // 16384
#define VOX   (1 << 21)       // 128^3
#define NCH   12

// Plane-interleaved de-aliased layout: S[d][ch][h][w].
// ch stride = 32 KB + 128 B; d stride = 12 ch strides (~395 KB, non-pow2).
// kmse's 24 streams per block now span ~790 KB (DRAM-row locality) instead
// of 2 x 48 MB. f123's per-wave write pattern is unchanged.
#define CSTR  (PLANE + 64)           // halves
#define DSTR  (NCH * CSTR)           // halves
#define IMGS  (DIM * DSTR + 512)     // halves (~50.5 MB)

typedef __attribute__((ext_vector_type(2))) _Float16 half2v;
typedef __attribute__((ext_vector_type(4))) _Float16 half4v;

// Per-channel shift pairs (d,h,w) = 2*(one_hot_idx - 1); verified (absmax 0).
__constant__ int c_sd1[12] = { 0, 0, 0, 0, 0, 2, 2, 2, 0, 0, 0, 0};
__constant__ int c_sh1[12] = { 0,-2,-2, 0, 0, 0, 0, 0, 2, 2, 2, 2};
__constant__ int c_sw1[12] = {-2, 0, 0, 2, 2, 0, 0, 0, 0, 0, 0, 0};
__constant__ int c_sd2[12] = {-2,-2, 0,-2, 0, 0, 0, 0,-2, 0, 0, 2};
__constant__ int c_sh2[12] = { 0, 0, 0, 0,-2, 0,-2, 0, 0, 0, 0, 0};
__constant__ int c_sw2[12] = { 0, 0,-2, 0, 0,-2, 0, 2, 0,-2, 2, 0};

__device__ __forceinline__ int clamp7(int v) { return min(max(v, 0), DMASK); }

// F123 = exact r15 wave-autonomous version (68 us; zero LDS, zero barriers,
// launch_bounds(256,3) — (256,6) spilled catastrophically in r16), with only
// the output-plane base arithmetic changed for the S[d][ch][h][w] layout.
__global__ __launch_bounds__(256, 3) void f123(const float* __restrict__ img0,
                                               const float* __restrict__ img1,
                                               _Float16* __restrict__ Sall) {
    const float* img = blockIdx.y ? img1 : img0;
    _Float16* outS = Sall + (size_t)blockIdx.y * IMGS;
    const char* imgc = (const char*)img;

    int wid = (blockIdx.x << 2) + (threadIdx.x >> 6);  // 0..1535
    int ch = wid >> 7;                 // 12
    int hs = (wid >> 3) & 15;          // 16 h-slices of 8 rows
    int ds = wid & 7;                  // 8 d-segs of 16 planes
    int h0 = hs << 3;
    int d0 = ds << 4;
    int l  = threadIdx.x & 63;

    int sd1 = c_sd1[ch], sh1 = c_sh1[ch], sw1 = c_sw1[ch];
    int sd2 = c_sd2[ch], sh2 = c_sh2[ch], sw2 = c_sw2[ch];

    // wave-uniform row byte-offsets (double clamp composed), 12 rows
    int rowOffA[12], rowOffB[12];
#pragma unroll
    for (int r = 0; r < 12; ++r) {
        int hq = clamp7(h0 - 2 + r);
        rowOffA[r] = clamp7(hq + sh1) * (DIM * 4);
        rowOffB[r] = clamp7(hq + sh2) * (DIM * 4);
    }

    // per-lane column byte bases (float2 at cols 2l+sw, clamped to [0,126])
    int c2 = l << 1;
    int colA = min(max(c2 + sw1, 0), 126) * 4;
    int colB = min(max(c2 + sw2, 0), 126) * 4;
    bool fixAlo = (sw1 < 0) && (l == 0);   // need (v0,v0): a.y = a.x
    bool fixAhi = (sw1 > 0) && (l == 63);  // need (v127,v127): a.x = a.y
    bool fixBlo = (sw2 < 0) && (l == 0);
    bool fixBhi = (sw2 > 0) && (l == 63);

    float2 win[8];
    half2v hist[5][8];
#pragma unroll
    for (int k = 0; k < 8; ++k) {
        win[k].x = 0.0f; win[k].y = 0.0f;
#pragma unroll
        for (int s = 0; s < 5; ++s) hist[s][k] = half2v{(_Float16)0.0f, (_Float16)0.0f};
    }

    _Float16* dstBase = outS + (size_t)ch * CSTR + h0 * DIM + c2;

    for (int oo = 0; oo < 4; ++oo) {
#pragma unroll
        for (int s5 = 0; s5 < 5; ++s5) {
            int it = oo * 5 + s5;
            int dp = clamp7(d0 - 2 + it);
            int pOffA = clamp7(dp + sd1) * (PLANE * 4);
            int pOffB = clamp7(dp + sd2) * (PLANE * 4);

            float tX[12], tY[12];
#pragma unroll
            for (int r = 0; r < 12; ++r) {
                float2 a = *(const float2*)(imgc + (pOffA + rowOffA[r] + colA));
                float2 b = *(const float2*)(imgc + (pOffB + rowOffB[r] + colB));
                a.y = fixAlo ? a.x : a.y;  a.x = fixAhi ? a.y : a.x;
                b.y = fixBlo ? b.x : b.y;  b.x = fixBhi ? b.y : b.x;
                float dx = a.x - b.x; dx *= dx;      // D2[2l]
                float dy = a.y - b.y; dy *= dy;      // D2[2l+1]
                float lx = __shfl_up(dx, 1, 64);     // D2[2l-2]
                float ly = __shfl_up(dy, 1, 64);     // D2[2l-1]
                float rx = __shfl_down(dx, 1, 64);   // D2[2l+2]
                float ry = __shfl_down(dy, 1, 64);   // D2[2l+3]
                ly = (l == 0)  ? dx : ly;            // D2[-1 -> 0]
                rx = (l == 63) ? dy : rx;            // D2[128 -> 127]
                tX[r] = lx + ly + dx + dy + rx;      // W-box(2l)
                tY[r] = ly + dx + dy + rx + ry;      // W-box(2l+1)
            }

            // H-box sliding 5-row sums + D-window update
            float sx = tX[0] + tX[1] + tX[2] + tX[3] + tX[4];
            float sy = tY[0] + tY[1] + tY[2] + tY[3] + tY[4];
            bool dowrite = (it >= 4);
            _Float16* dstD = dstBase + (size_t)(d0 + it - 4) * DSTR;
#pragma unroll
            for (int k = 0; k < 8; ++k) {
                half2v hv = { (_Float16)sx, (_Float16)sy };  // round first (validated)
                half2v old = hist[s5][k];
                win[k].x += (float)hv[0] - (float)old[0];
                win[k].y += (float)hv[1] - (float)old[1];
                hist[s5][k] = hv;
                if (dowrite) {
                    half2v ov = { (_Float16)win[k].x, (_Float16)win[k].y };
                    *(half2v*)(dstD + k * DIM) = ov;
                }
                if (k < 7) {
                    sx += tX[k + 5] - tX[k];
                    sy += tY[k + 5] - tY[k];
                }
            }
        }
    }
}

// kmse v8: 4 vox/thread, 24 independent 8-B loads; with S[d][ch][h][w] the
// block's 24 streams span ~790 KB -> DRAM row locality. No atomics.
__global__ __launch_bounds__(256, 3) void kmse(const _Float16* __restrict__ S0,
                                               const _Float16* __restrict__ S1,
                                               float* __restrict__ partial) {
    int t   = blockIdx.x * 256 + threadIdx.x;     // 2048 blocks
    int idx = t << 2;
    int d   = idx >> 14;
    int hw  = idx & (PLANE - 1);

    const _Float16* p0 = S0 + (size_t)d * DSTR + hw;
    const _Float16* p1 = S1 + (size_t)d * DSTR + hw;

    half4v v0[NCH], v1[NCH];
#pragma unroll
    for (int ch = 0; ch < NCH; ++ch)
        v0[ch] = *(const half4v*)(p0 + ch * CSTR);
#pragma unroll
    for (int ch = 0; ch < NCH; ++ch)
        v1[ch] = *(const half4v*)(p1 + ch * CSTR);

    float mn0[4], sm0[4], mn1[4], sm1[4];
#pragma unroll
    for (int j = 0; j < 4; ++j) {
        mn0[j] = 3.4e38f; sm0[j] = 0.0f;
        mn1[j] = 3.4e38f; sm1[j] = 0.0f;
    }
#pragma unroll
    for (int ch = 0; ch < NCH; ++ch)
#pragma unroll
        for (int j = 0; j < 4; ++j) {
            float s0 = (float)v0[ch][j];
            float s1 = (float)v1[ch][j];
            mn0[j] = fminf(mn0[j], s0); sm0[j] += s0;
            mn1[j] = fminf(mn1[j], s1); sm1[j] += s1;
        }

    float inv0[4], inv1[4];
#pragma unroll
    for (int j = 0; j < 4; ++j) {
        inv0[j] = __fdividef(1.0f, sm0[j] * (1.0f / 12.0f) - mn0[j]);
        inv1[j] = __fdividef(1.0f, sm1[j] * (1.0f / 12.0f) - mn1[j]);
    }

    float acc = 0.0f;
#pragma unroll
    for (int ch = 0; ch < NCH; ++ch)
#pragma unroll
        for (int j = 0; j < 4; ++j) {
            float e0 = __expf(-((float)v0[ch][j] - mn0[j]) * inv0[j]);
            float e1 = __expf(-((float)v1[ch][j] - mn1[j]) * inv1[j]);
            float df = e0 - e1;
            acc += df * df;
        }

#pragma unroll
    for (int off = 32; off > 0; off >>= 1)
        acc += __shfl_down(acc, off, 64);
    __shared__ float smem[4];
    int lane = threadIdx.x & 63, wv = threadIdx.x >> 6;
    if (lane == 0) smem[wv] = acc;
    __syncthreads();
    if (threadIdx.x == 0)
        partial[blockIdx.x] = smem[0] + smem[1] + smem[2] + smem[3];
}

// kred: sum 2048 partials, write the final scalar.
__global__ __launch_bounds__(256) void kred(const float* __restrict__ partial,
                                            float* __restrict__ out) {
    int tid = threadIdx.x;
    float acc = 0.0f;
#pragma unroll
    for (int k = 0; k < 8; ++k)
        acc += partial[tid + (k << 8)];
#pragma unroll
    for (int off = 32; off > 0; off >>= 1)
        acc += __shfl_down(acc, off, 64);
    __shared__ float smem[4];
    int lane = tid & 63, wv = tid >> 6;
    if (lane == 0) smem[wv] = acc;
    __syncthreads();
    if (tid == 0)
        out[0] = (smem[0] + smem[1] + smem[2] + smem[3])
               * (1.0f / (12.0f * (float)VOX));
}

__global__ void kdiag(float* out, float ws_mb) { out[0] = ws_mb; }

extern "C" void kernel_launch(void* const* d_in, const int* in_sizes, int n_in,
                              void* d_out, int out_size, void* d_ws, size_t ws_size,
                              hipStream_t stream) {
    const float* y_true = (const float*)d_in[0];
    const float* y_pred = (const float*)d_in[1];
    float* out = (float*)d_out;

    const size_t NEED = 2ull * IMGS * sizeof(_Float16) + 8192 + 64;  // ~101 MB
    if (ws_size < NEED) {
        kdiag<<<1, 1, 0, stream>>>(out, (float)(ws_size >> 20));
        return;
    }

    _Float16* S0      = (_Float16*)d_ws;            // ssd img0 [d][ch][h][w]
    _Float16* S1      = S0 + (size_t)IMGS;          // ssd img1
    float*    partial = (float*)(S1 + (size_t)IMGS);// 2048 floats

    // 1536 wave-tasks per image (12 ch x 16 hslices x 8 dsegs), 4 waves/block
    f123<<<dim3(384, 2), 256, 0, stream>>>(y_true, y_pred, S0);
    kmse<<<VOX / 4 / 256, 256, 0, stream>>>(S0, S1, partial);
    kred<<<1, 256, 0, stream>>>(partial, out);
}